// Round 17
// baseline (236.010 us; speedup 1.0000x reference)
//
#include <hip/hip_runtime.h>

#define E_ 131072

typedef _Float16 half8 __attribute__((ext_vector_type(8)));
typedef float f32x4 __attribute__((ext_vector_type(4)));

__device__ __forceinline__ float gelu_f(float x) {
    return 0.5f * x * (1.0f + erff(x * 0.70710678118654752f));
}

#define TWOPI_64 (6.2831853071795864769f / 64.0f)

__device__ __forceinline__ void block_reduce2(float& s, float& s2, float* red) {
    #pragma unroll
    for (int off = 32; off > 0; off >>= 1) {
        s  += __shfl_down(s, off, 64);
        s2 += __shfl_down(s2, off, 64);
    }
    int lane = threadIdx.x & 63, wv = threadIdx.x >> 6;
    __syncthreads();
    if (lane == 0) { red[wv] = s; red[wv + 4] = s2; }
    __syncthreads();
    s  = red[0] + red[1] + red[2] + red[3];
    s2 = red[4] + red[5] + red[6] + red[7];
}

// 16-wave variant for 1024-thread blocks
__device__ __forceinline__ void block_reduce2_w16(float& s, float& s2, float* red) {
    #pragma unroll
    for (int off = 32; off > 0; off >>= 1) {
        s  += __shfl_down(s, off, 64);
        s2 += __shfl_down(s2, off, 64);
    }
    int lane = threadIdx.x & 63, wv = threadIdx.x >> 6;
    __syncthreads();
    if (lane == 0) { red[wv] = s; red[wv + 16] = s2; }
    __syncthreads();
    float a = 0.f, b = 0.f;
    #pragma unroll
    for (int w = 0; w < 16; ++w) { a += red[w]; b += red[w + 16]; }
    s = a; s2 = b;
}

// ---- GNO 64-edge chunk body (R9/R10-verified: f16 W2, hi/lo activations,
// kb2 direct from global, LDS 19456 B) ----
__device__ __forceinline__ void gno_body(int e0, float* sbufF, int* ssrc, int* sdst,
                                         const float* __restrict__ ea,
                                         const float* __restrict__ kw1, const float* __restrict__ kb1,
                                         const float* __restrict__ kb2,
                                         const _Float16* __restrict__ whi,
                                         const float* __restrict__ xn, const int* __restrict__ ei,
                                         float* __restrict__ agg) {
    _Float16* sxTh = (_Float16*)sbufF;
    int t = threadIdx.x;
    int lane = t & 63, wv = t >> 6, quad = lane >> 4, l15 = lane & 15;
    int eg = wv >> 1, t2 = wv & 1;

    if (t < 64) ssrc[t] = ei[e0 + t];
    else if (t < 128) sdst[t - 64] = ei[E_ + e0 + t - 64];
    {
        int r = t >> 2, k0 = (t & 3) * 16;
        const float* ep = ea + (e0 + r) * 6;
        float e6[6];
        #pragma unroll
        for (int d = 0; d < 6; ++d) e6[d] = ep[d];
        #pragma unroll
        for (int kk = 0; kk < 16; ++kk) {
            int k = k0 + kk;
            float acc = kb1[k];
            #pragma unroll
            for (int d = 0; d < 6; ++d) acc += e6[d] * kw1[d * 64 + k];
            sbufF[r * 68 + k] = gelu_f(acc);
        }
    }
    __syncthreads();
    half8 ahi[2][2], alo[2][2];
    #pragma unroll
    for (int et = 0; et < 2; ++et) {
        #pragma unroll
        for (int kh = 0; kh < 2; ++kh) {
            const float* hp = sbufF + (eg * 32 + et * 16 + l15) * 68 + kh * 32 + quad * 8;
            float4 h0 = *(const float4*)hp;
            float4 h1 = *(const float4*)(hp + 4);
            float hv[8] = {h0.x, h0.y, h0.z, h0.w, h1.x, h1.y, h1.z, h1.w};
            half8 hh, hl;
            #pragma unroll
            for (int j = 0; j < 8; ++j) {
                _Float16 hi = (_Float16)hv[j];
                hh[j] = hi;
                hl[j] = (_Float16)(hv[j] - (float)hi);
            }
            ahi[et][kh] = hh;
            alo[et][kh] = hl;
        }
    }
    __syncthreads();
    {
        int b = t & 3, r = t >> 2;
        int s = ssrc[r];
        int pe = (r >> 5) * 32 + ((r >> 2) & 3) * 8 + ((r >> 4) & 1) * 4 + (r & 3);
        const float4* xp = (const float4*)(xn + (b * 4096 + s) * 32);
        _Float16* dp = sxTh + b * 2312 + pe;
        #pragma unroll
        for (int q = 0; q < 8; ++q) {
            float4 v = xp[q];
            dp[(q * 4 + 0) * 72] = (_Float16)v.x;
            dp[(q * 4 + 1) * 72] = (_Float16)v.y;
            dp[(q * 4 + 2) * 72] = (_Float16)v.z;
            dp[(q * 4 + 3) * 72] = (_Float16)v.w;
        }
    }
    __syncthreads();
    float msg[4][2][4];
    #pragma unroll
    for (int b = 0; b < 4; ++b)
        #pragma unroll
        for (int et = 0; et < 2; ++et)
            #pragma unroll
            for (int r = 0; r < 4; ++r) msg[b][et][r] = 0.f;

    for (int i = 0; i < 32; ++i) {
        float b2v = kb2[i * 32 + t2 * 16 + l15];
        int f0 = (i * 4 + t2 * 2) * 512 + lane * 8;
        half8 bhi0 = *(const half8*)(whi + f0);
        half8 bhi1 = *(const half8*)(whi + f0 + 512);
        f32x4 acc[2];
        #pragma unroll
        for (int et = 0; et < 2; ++et) {
            f32x4 ac = {b2v, b2v, b2v, b2v};
            ac = __builtin_amdgcn_mfma_f32_16x16x32_f16(ahi[et][0], bhi0, ac, 0, 0, 0);
            ac = __builtin_amdgcn_mfma_f32_16x16x32_f16(ahi[et][1], bhi1, ac, 0, 0, 0);
            ac = __builtin_amdgcn_mfma_f32_16x16x32_f16(alo[et][0], bhi0, ac, 0, 0, 0);
            ac = __builtin_amdgcn_mfma_f32_16x16x32_f16(alo[et][1], bhi1, ac, 0, 0, 0);
            acc[et] = ac;
        }
        #pragma unroll
        for (int b = 0; b < 4; ++b) {
            const half8 xv = *(const half8*)(sxTh + b * 2312 + i * 72 + eg * 32 + quad * 8);
            #pragma unroll
            for (int et = 0; et < 2; ++et) {
                msg[b][et][0] += (float)xv[et * 4 + 0] * acc[et][0];
                msg[b][et][1] += (float)xv[et * 4 + 1] * acc[et][1];
                msg[b][et][2] += (float)xv[et * 4 + 2] * acc[et][2];
                msg[b][et][3] += (float)xv[et * 4 + 3] * acc[et][3];
            }
        }
    }
    int o = t2 * 16 + l15;
    #pragma unroll
    for (int et = 0; et < 2; ++et) {
        #pragma unroll
        for (int r = 0; r < 4; ++r) {
            int row = eg * 32 + et * 16 + quad * 4 + r;
            int d = sdst[row];
            #pragma unroll
            for (int b = 0; b < 4; ++b) {
                atomicAdd(&agg[(b * 4096 + d) * 32 + o], msg[b][et][r]);
            }
        }
    }
}

// ---------------- L1 (1024 threads): 0..255 IN+full DFT | 256..271 w2 repack ----------------
__global__ __launch_bounds__(1024, 1) void k_pre(const float* __restrict__ nodes,
                                                 const float* __restrict__ w2,
                                                 float* __restrict__ xn,
                                                 float* __restrict__ agg,
                                                 float* __restrict__ Gre, float* __restrict__ Gim,
                                                 _Float16* __restrict__ whi) {
    int t = threadIdx.x;
    if (blockIdx.x >= 256) {
        int g0 = (blockIdx.x - 256) * 4096 + t;
        #pragma unroll
        for (int r = 0; r < 4; ++r) {
            int g = g0 + r * 1024;
            int j = g & 7, l = (g >> 3) & 63, fid = g >> 9;
            int i = fid >> 2, t2 = (fid >> 1) & 1, kh = fid & 1;
            int quad = l >> 4, l15 = l & 15;
            int k = kh * 32 + quad * 8 + j;
            int n = i * 32 + t2 * 16 + l15;
            whi[g] = (_Float16)w2[k * 1024 + n];
        }
        return;
    }
    int bh = blockIdx.x;
    __shared__ float sx[2048];
    __shared__ float tc[64], ts[64];
    __shared__ float red[32];
    __shared__ float pre_[1024], pim_[1024];
    const float2* src = (const float2*)(nodes + bh * 2048);
    if (t < 64) { float a = TWOPI_64 * t; tc[t] = cosf(a); ts[t] = sinf(a); }
    float2 v = src[t];
    float s  = v.x + v.y;
    float s2 = v.x * v.x + v.y * v.y;
    block_reduce2_w16(s, s2, red);
    float mean = s * (1.0f / 2048.0f);
    float var  = s2 * (1.0f / 2048.0f) - mean * mean;
    float sc = rsqrtf(var + 1e-5f);
    v.x = (v.x - mean) * sc;
    v.y = (v.y - mean) * sc;
    ((float2*)(xn + bh * 2048))[t] = v;
    float2 z = {0.f, 0.f};
    ((float2*)(agg + bh * 2048))[t] = z;
    sx[t * 2] = v.x;
    sx[t * 2 + 1] = v.y;
    __syncthreads();
    {
        int oi = t & 511, half = t >> 9;
        int ky = oi >> 5, i = oi & 31;
        float re = 0.f, im = 0.f;
        int w0 = half * 32;
        #pragma unroll 8
        for (int w = w0; w < w0 + 32; ++w) {
            float vv = sx[w * 32 + i];
            int m = (ky * w) & 63;
            re += vv * tc[m];
            im -= vv * ts[m];
        }
        pre_[t] = re;
        pim_[t] = im;
    }
    __syncthreads();
    if (t < 512) {
        Gre[bh * 512 + t] = pre_[t] + pre_[t + 512];
        Gim[bh * 512 + t] = pim_[t] + pim_[t + 512];
    }
}

// ---------------- L2: 0..2047 GNO chunks | 2048..2175 fxy | 2176..2431 x2 ----------------
// R17: long GNO blocks dispatch FIRST; short fxy/x2 blocks dispatch LAST so they
// backfill the GNO drain tail instead of long blocks finishing at low occupancy.
__global__ __launch_bounds__(256, 4) void k_g1(
        const float* __restrict__ Gre, const float* __restrict__ Gim,
        const float* __restrict__ w1re, const float* __restrict__ w1im,
        const float* __restrict__ w2re, const float* __restrict__ w2im,
        float* __restrict__ Yr, float* __restrict__ Yi,
        const float* __restrict__ ww1, const float* __restrict__ wb1,
        const float* __restrict__ ww2, const float* __restrict__ wb2,
        float* __restrict__ osum,
        const float* __restrict__ ea,
        const float* __restrict__ kw1, const float* __restrict__ kb1,
        const float* __restrict__ kb2,
        const _Float16* __restrict__ whi,
        const float* __restrict__ xn,
        const int* __restrict__ ei,
        float* __restrict__ agg) {
    __shared__ __align__(16) float U[4624];
    __shared__ int ssrc[64], sdst[64];
    int t = threadIdx.x;

    if (blockIdx.x < 2048) {
        gno_body(blockIdx.x * 64, U, ssrc, sdst,
                 ea, kw1, kb1, kb2, whi, xn, ei, agg);
        return;
    }
    if (blockIdx.x < 2176) {
        // ---- fxy ----
        float* tc  = U;
        float* ts  = U + 64;
        float* sXr = U + 128;
        float* sXi = U + 656;
        int bid = blockIdx.x - 2048;
        int b = bid >> 5, kxi = bid & 31;
        int kx = kxi + (kxi < 16 ? 0 : 32);
        int x = kxi & 15;
        const float* wre = (kxi < 16) ? w1re : w2re;
        const float* wim = (kxi < 16) ? w1im : w2im;
        if (t < 64) { float a = TWOPI_64 * t; tc[t] = cosf(a); ts[t] = sinf(a); }
        __syncthreads();
        #pragma unroll 1
        for (int rep = 0; rep < 2; ++rep) {
            int oi = rep * 256 + t;
            int ky = oi >> 5, i = oi & 31;
            float re = 0.f, im = 0.f;
            #pragma unroll 8
            for (int h = 0; h < 64; ++h) {
                int gidx = (b * 64 + h) * 512 + ky * 32 + i;
                float gr = Gre[gidx], gi = Gim[gidx];
                int m = (kx * h) & 63;
                float c = tc[m], sv = ts[m];
                re += gr * c + gi * sv;
                im += gi * c - gr * sv;
            }
            sXr[ky * 33 + i] = re;
            sXi[ky * 33 + i] = im;
        }
        __syncthreads();
        #pragma unroll 1
        for (int rep = 0; rep < 2; ++rep) {
            int oi = rep * 256 + t;
            int ky = oi & 15, o = oi >> 4;
            float re = 0.f, im = 0.f;
            #pragma unroll 4
            for (int i = 0; i < 32; ++i) {
                float xr = sXr[ky * 33 + i], xi = sXi[ky * 33 + i];
                int widx = (i * 32 + o) * 256 + x * 16 + ky;
                float wr = wre[widx], wi = wim[widx];
                re += xr * wr - xi * wi;
                im += xr * wi + xi * wr;
            }
            Yr[bid * 512 + ky * 32 + o] = re;
            Yi[bid * 512 + ky * 32 + o] = im;
        }
        return;
    }
    {
        // ---- x2 = IN(MLP(xn)) -> osum; sHh @ U+2120 ends 4424 <= 4624 ----
        int bh = blockIdx.x - 2176;
        float* red = U;
        float* sX = U + 8;                      // 8..2120
        _Float16* sHh = (_Float16*)(U + 2120);  // 2304 floats -> ends 4424
        for (int f = t; f < 2048; f += 256) sX[(f >> 5) * 33 + (f & 31)] = xn[bh * 2048 + f];
        __syncthreads();
        #pragma unroll 1
        for (int rep = 0; rep < 16; ++rep) {
            int idx = rep * 256 + t;
            int w = idx >> 6, k = idx & 63;
            float acc = wb1[k];
            #pragma unroll 4
            for (int c = 0; c < 32; ++c) acc += sX[w * 33 + c] * ww1[c * 64 + k];
            sHh[w * 72 + k] = (_Float16)gelu_f(acc);
        }
        __syncthreads();
        float s = 0.f, s2 = 0.f;
        #pragma unroll 1
        for (int rep = 0; rep < 8; ++rep) {
            int idx = rep * 256 + t;
            int w = idx >> 5, o = idx & 31;
            float acc = wb2[o];
            #pragma unroll 4
            for (int k = 0; k < 64; ++k) acc += (float)sHh[w * 72 + k] * ww2[k * 32 + o];
            sX[w * 33 + o] = acc;
            s += acc; s2 += acc * acc;
        }
        block_reduce2(s, s2, red);
        float mean = s * (1.0f / 2048.0f);
        float sc = rsqrtf(s2 * (1.0f / 2048.0f) - mean * mean + 1e-5f);
        #pragma unroll 1
        for (int rep = 0; rep < 8; ++rep) {
            int idx = rep * 256 + t;
            int w = idx >> 5, o = idx & 31;
            osum[bh * 2048 + idx] = (sX[w * 33 + o] - mean) * sc;
        }
    }
}

// ---------------- L3 (fused, 1024 threads): zx1 + final output, 256 blocks ----------------
__global__ __launch_bounds__(1024, 1) void k_g2f(
        const float* __restrict__ Yr, const float* __restrict__ Yi,
        const float* __restrict__ mw1, const float* __restrict__ mb1,
        const float* __restrict__ mw2, const float* __restrict__ mb2,
        const float* __restrict__ osum, const float* __restrict__ agg,
        const float* __restrict__ xn, const float* __restrict__ root,
        const float* __restrict__ gbias, float* __restrict__ out) {
    __shared__ __align__(16) float U[8768];
    int t = threadIdx.x;
    int bh = blockIdx.x;
    int b = bh >> 6, h = bh & 63;
    float* tc  = U;                          // 0..64
    float* ts  = U + 64;                     // 64..128
    float* red = U + 128;                    // 128..160 (32 for 16-wave reduce)
    float* sZr = U + 160;                    // 160..688
    float* sZi = U + 688;                    // 688..1216
    float* sP  = U + 1216;                   // 1216..3328
    float* pZr = U + 1216;                   // Z-phase partials (dead sP region)
    float* pZi = U + 2240;                   // 2240..3264
    _Float16* sHh = (_Float16*)(U + 3328);   // 2304 floats -> 3328..5632
    float* sX  = U + 5632;                   // 5632..7744 (xn, 64x33)
    float* sR  = U + 7744;                   // 7744..8768 (root)

    // early loads for the fused final stage
    for (int f = t; f < 2048; f += 1024) sX[(f >> 5) * 33 + (f & 31)] = xn[bh * 2048 + f];
    sR[t] = root[t];
    float osv[2], agv[2];
    #pragma unroll
    for (int rep = 0; rep < 2; ++rep) {
        int idx = rep * 1024 + t;
        osv[rep] = osum[bh * 2048 + idx];
        agv[rep] = agg[bh * 2048 + idx];
    }
    if (t < 64) { float a = TWOPI_64 * t; tc[t] = cosf(a); ts[t] = sinf(a); }
    __syncthreads();
    {
        int oi = t & 511, half = t >> 9;
        int ky = oi >> 5, o = oi & 31;
        float re = 0.f, im = 0.f;
        int k0 = half * 16;
        #pragma unroll 4
        for (int kxi = k0; kxi < k0 + 16; ++kxi) {
            int kx = kxi + (kxi < 16 ? 0 : 32);
            int m = (kx * h) & 63;
            float c = tc[m], sv = ts[m];
            int yidx = (b * 32 + kxi) * 512 + ky * 32 + o;
            float yr = Yr[yidx], yi = Yi[yidx];
            re += yr * c - yi * sv;
            im += yr * sv + yi * c;
        }
        pZr[t] = re;
        pZi[t] = im;
    }
    __syncthreads();
    if (t < 512) {
        int ky = t >> 5, o = t & 31;
        sZr[ky * 33 + o] = pZr[t] + pZr[t + 512];
        sZi[ky * 33 + o] = pZi[t] + pZi[t + 512];
    }
    __syncthreads();
    float s = 0.f, s2 = 0.f;
    #pragma unroll 1
    for (int rep = 0; rep < 2; ++rep) {
        int idx = rep * 1024 + t;
        int w = idx >> 5, o = idx & 31;
        float acc = sZr[o];  // ky=0: real part only (irfft drops imag of DC bin)
        #pragma unroll
        for (int ky = 1; ky < 16; ++ky) {
            int m = (ky * w) & 63;
            acc += 2.0f * (sZr[ky * 33 + o] * tc[m] - sZi[ky * 33 + o] * ts[m]);
        }
        acc *= (1.0f / 4096.0f);
        sP[w * 33 + o] = acc;
        s += acc; s2 += acc * acc;
    }
    block_reduce2_w16(s, s2, red);
    float mean = s * (1.0f / 2048.0f);
    float sc = rsqrtf(s2 * (1.0f / 2048.0f) - mean * mean + 1e-5f);
    #pragma unroll 1
    for (int rep = 0; rep < 2; ++rep) {
        int idx = rep * 1024 + t;
        int w = idx >> 5, o = idx & 31;
        sP[w * 33 + o] = (sP[w * 33 + o] - mean) * sc;
    }
    __syncthreads();
    #pragma unroll 1
    for (int rep = 0; rep < 4; ++rep) {
        int idx = rep * 1024 + t;
        int w = idx >> 6, k = idx & 63;
        float acc = mb1[k];
        #pragma unroll 4
        for (int c = 0; c < 32; ++c) acc += sP[w * 33 + c] * mw1[c * 64 + k];
        sHh[w * 72 + k] = (_Float16)gelu_f(acc);
    }
    __syncthreads();
    #pragma unroll 1
    for (int rep = 0; rep < 2; ++rep) {
        int idx = rep * 1024 + t;
        int w = idx >> 5, o = idx & 31;
        float x1v = mb2[o];
        #pragma unroll 4
        for (int k = 0; k < 64; ++k) x1v += (float)sHh[w * 72 + k] * mw2[k * 32 + o];
        float val = gbias[o] + osv[rep] + agv[rep] + x1v;
        #pragma unroll 4
        for (int c = 0; c < 32; ++c) val += sX[w * 33 + c] * sR[c * 32 + o];
        out[bh * 2048 + idx] = gelu_f(val);
    }
}

extern "C" void kernel_launch(void* const* d_in, const int* in_sizes, int n_in,
                              void* d_out, int out_size, void* d_ws, size_t ws_size,
                              hipStream_t stream) {
    (void)in_sizes; (void)n_in; (void)out_size; (void)ws_size;
    const float* nodes  = (const float*)d_in[0];
    const int*   eidx   = (const int*)d_in[1];
    const float* eattr  = (const float*)d_in[2];
    const float* w1re   = (const float*)d_in[3];
    const float* w1im   = (const float*)d_in[4];
    const float* w2re   = (const float*)d_in[5];
    const float* w2im   = (const float*)d_in[6];
    const float* mlp_w1 = (const float*)d_in[7];
    const float* mlp_b1 = (const float*)d_in[8];
    const float* mlp_w2 = (const float*)d_in[9];
    const float* mlp_b2 = (const float*)d_in[10];
    const float* wm_w1  = (const float*)d_in[11];
    const float* wm_b1  = (const float*)d_in[12];
    const float* wm_w2  = (const float*)d_in[13];
    const float* wm_b2  = (const float*)d_in[14];
    const float* ker_w1 = (const float*)d_in[15];
    const float* ker_b1 = (const float*)d_in[16];
    const float* ker_w2 = (const float*)d_in[17];
    const float* ker_b2 = (const float*)d_in[18];
    const float* root   = (const float*)d_in[19];
    const float* gbias  = (const float*)d_in[20];
    float* out = (float*)d_out;

    char* ws = (char*)d_ws;
    size_t off = 0;
    auto alloc = [&](size_t bytes) {
        void* p = ws + off;
        off += (bytes + 255) & ~(size_t)255;
        return p;
    };
    float* xn   = (float*)alloc(524288 * 4);
    float* agg  = (float*)alloc(524288 * 4);
    float* osum = (float*)alloc(524288 * 4);
    float* Gre  = (float*)alloc(131072 * 4);
    float* Gim  = (float*)alloc(131072 * 4);
    float* Yr   = (float*)alloc(65536 * 4);
    float* Yi   = (float*)alloc(65536 * 4);
    _Float16* whi = (_Float16*)alloc(65536 * 2);

    k_pre<<<272, 1024, 0, stream>>>(nodes, ker_w2, xn, agg, Gre, Gim, whi);
    k_g1<<<2432, 256, 0, stream>>>(Gre, Gim, w1re, w1im, w2re, w2im, Yr, Yi,
                                   wm_w1, wm_b1, wm_w2, wm_b2, osum,
                                   eattr, ker_w1, ker_b1, ker_b2, whi, xn, eidx, agg);
    k_g2f<<<256, 1024, 0, stream>>>(Yr, Yi, mlp_w1, mlp_b1, mlp_w2, mlp_b2,
                                    osum, agg, xn, root, gbias, out);
}

// Round 18
// 217.801 us; speedup vs baseline: 1.0836x; 1.0836x over previous
//
#include <hip/hip_runtime.h>

#define E_ 131072

typedef _Float16 half8 __attribute__((ext_vector_type(8)));
typedef float f32x4 __attribute__((ext_vector_type(4)));

__device__ __forceinline__ float gelu_f(float x) {
    return 0.5f * x * (1.0f + erff(x * 0.70710678118654752f));
}

#define TWOPI_64 (6.2831853071795864769f / 64.0f)

__device__ __forceinline__ void block_reduce2(float& s, float& s2, float* red) {
    #pragma unroll
    for (int off = 32; off > 0; off >>= 1) {
        s  += __shfl_down(s, off, 64);
        s2 += __shfl_down(s2, off, 64);
    }
    int lane = threadIdx.x & 63, wv = threadIdx.x >> 6;
    __syncthreads();
    if (lane == 0) { red[wv] = s; red[wv + 4] = s2; }
    __syncthreads();
    s  = red[0] + red[1] + red[2] + red[3];
    s2 = red[4] + red[5] + red[6] + red[7];
}

// 16-wave variant for 1024-thread blocks
__device__ __forceinline__ void block_reduce2_w16(float& s, float& s2, float* red) {
    #pragma unroll
    for (int off = 32; off > 0; off >>= 1) {
        s  += __shfl_down(s, off, 64);
        s2 += __shfl_down(s2, off, 64);
    }
    int lane = threadIdx.x & 63, wv = threadIdx.x >> 6;
    __syncthreads();
    if (lane == 0) { red[wv] = s; red[wv + 16] = s2; }
    __syncthreads();
    float a = 0.f, b = 0.f;
    #pragma unroll
    for (int w = 0; w < 16; ++w) { a += red[w]; b += red[w + 16]; }
    s = a; s2 = b;
}

// ---- GNO 64-edge chunk body (R9/R10-verified: f16 W2, hi/lo activations,
// kb2 direct from global, LDS 19456 B) ----
__device__ __forceinline__ void gno_body(int e0, float* sbufF, int* ssrc, int* sdst,
                                         const float* __restrict__ ea,
                                         const float* __restrict__ kw1, const float* __restrict__ kb1,
                                         const float* __restrict__ kb2,
                                         const _Float16* __restrict__ whi,
                                         const float* __restrict__ xn, const int* __restrict__ ei,
                                         float* __restrict__ agg) {
    _Float16* sxTh = (_Float16*)sbufF;
    int t = threadIdx.x;
    int lane = t & 63, wv = t >> 6, quad = lane >> 4, l15 = lane & 15;
    int eg = wv >> 1, t2 = wv & 1;

    if (t < 64) ssrc[t] = ei[e0 + t];
    else if (t < 128) sdst[t - 64] = ei[E_ + e0 + t - 64];
    {
        int r = t >> 2, k0 = (t & 3) * 16;
        const float* ep = ea + (e0 + r) * 6;
        float e6[6];
        #pragma unroll
        for (int d = 0; d < 6; ++d) e6[d] = ep[d];
        #pragma unroll
        for (int kk = 0; kk < 16; ++kk) {
            int k = k0 + kk;
            float acc = kb1[k];
            #pragma unroll
            for (int d = 0; d < 6; ++d) acc += e6[d] * kw1[d * 64 + k];
            sbufF[r * 68 + k] = gelu_f(acc);
        }
    }
    __syncthreads();
    half8 ahi[2][2], alo[2][2];
    #pragma unroll
    for (int et = 0; et < 2; ++et) {
        #pragma unroll
        for (int kh = 0; kh < 2; ++kh) {
            const float* hp = sbufF + (eg * 32 + et * 16 + l15) * 68 + kh * 32 + quad * 8;
            float4 h0 = *(const float4*)hp;
            float4 h1 = *(const float4*)(hp + 4);
            float hv[8] = {h0.x, h0.y, h0.z, h0.w, h1.x, h1.y, h1.z, h1.w};
            half8 hh, hl;
            #pragma unroll
            for (int j = 0; j < 8; ++j) {
                _Float16 hi = (_Float16)hv[j];
                hh[j] = hi;
                hl[j] = (_Float16)(hv[j] - (float)hi);
            }
            ahi[et][kh] = hh;
            alo[et][kh] = hl;
        }
    }
    __syncthreads();
    {
        int b = t & 3, r = t >> 2;
        int s = ssrc[r];
        int pe = (r >> 5) * 32 + ((r >> 2) & 3) * 8 + ((r >> 4) & 1) * 4 + (r & 3);
        const float4* xp = (const float4*)(xn + (b * 4096 + s) * 32);
        _Float16* dp = sxTh + b * 2312 + pe;
        #pragma unroll
        for (int q = 0; q < 8; ++q) {
            float4 v = xp[q];
            dp[(q * 4 + 0) * 72] = (_Float16)v.x;
            dp[(q * 4 + 1) * 72] = (_Float16)v.y;
            dp[(q * 4 + 2) * 72] = (_Float16)v.z;
            dp[(q * 4 + 3) * 72] = (_Float16)v.w;
        }
    }
    __syncthreads();
    float msg[4][2][4];
    #pragma unroll
    for (int b = 0; b < 4; ++b)
        #pragma unroll
        for (int et = 0; et < 2; ++et)
            #pragma unroll
            for (int r = 0; r < 4; ++r) msg[b][et][r] = 0.f;

    for (int i = 0; i < 32; ++i) {
        float b2v = kb2[i * 32 + t2 * 16 + l15];
        int f0 = (i * 4 + t2 * 2) * 512 + lane * 8;
        half8 bhi0 = *(const half8*)(whi + f0);
        half8 bhi1 = *(const half8*)(whi + f0 + 512);
        f32x4 acc[2];
        #pragma unroll
        for (int et = 0; et < 2; ++et) {
            f32x4 ac = {b2v, b2v, b2v, b2v};
            ac = __builtin_amdgcn_mfma_f32_16x16x32_f16(ahi[et][0], bhi0, ac, 0, 0, 0);
            ac = __builtin_amdgcn_mfma_f32_16x16x32_f16(ahi[et][1], bhi1, ac, 0, 0, 0);
            ac = __builtin_amdgcn_mfma_f32_16x16x32_f16(alo[et][0], bhi0, ac, 0, 0, 0);
            ac = __builtin_amdgcn_mfma_f32_16x16x32_f16(alo[et][1], bhi1, ac, 0, 0, 0);
            acc[et] = ac;
        }
        #pragma unroll
        for (int b = 0; b < 4; ++b) {
            const half8 xv = *(const half8*)(sxTh + b * 2312 + i * 72 + eg * 32 + quad * 8);
            #pragma unroll
            for (int et = 0; et < 2; ++et) {
                msg[b][et][0] += (float)xv[et * 4 + 0] * acc[et][0];
                msg[b][et][1] += (float)xv[et * 4 + 1] * acc[et][1];
                msg[b][et][2] += (float)xv[et * 4 + 2] * acc[et][2];
                msg[b][et][3] += (float)xv[et * 4 + 3] * acc[et][3];
            }
        }
    }
    int o = t2 * 16 + l15;
    #pragma unroll
    for (int et = 0; et < 2; ++et) {
        #pragma unroll
        for (int r = 0; r < 4; ++r) {
            int row = eg * 32 + et * 16 + quad * 4 + r;
            int d = sdst[row];
            #pragma unroll
            for (int b = 0; b < 4; ++b) {
                atomicAdd(&agg[(b * 4096 + d) * 32 + o], msg[b][et][r]);
            }
        }
    }
}

// ---------------- L1 (1024 threads): 0..255 IN+full DFT | 256..271 w2 repack ----------------
__global__ __launch_bounds__(1024, 1) void k_pre(const float* __restrict__ nodes,
                                                 const float* __restrict__ w2,
                                                 float* __restrict__ xn,
                                                 float* __restrict__ agg,
                                                 float* __restrict__ Gre, float* __restrict__ Gim,
                                                 _Float16* __restrict__ whi) {
    int t = threadIdx.x;
    if (blockIdx.x >= 256) {
        int g0 = (blockIdx.x - 256) * 4096 + t;
        #pragma unroll
        for (int r = 0; r < 4; ++r) {
            int g = g0 + r * 1024;
            int j = g & 7, l = (g >> 3) & 63, fid = g >> 9;
            int i = fid >> 2, t2 = (fid >> 1) & 1, kh = fid & 1;
            int quad = l >> 4, l15 = l & 15;
            int k = kh * 32 + quad * 8 + j;
            int n = i * 32 + t2 * 16 + l15;
            whi[g] = (_Float16)w2[k * 1024 + n];
        }
        return;
    }
    int bh = blockIdx.x;
    __shared__ float sx[2048];
    __shared__ float tc[64], ts[64];
    __shared__ float red[32];
    __shared__ float pre_[1024], pim_[1024];
    const float2* src = (const float2*)(nodes + bh * 2048);
    if (t < 64) { float a = TWOPI_64 * t; tc[t] = cosf(a); ts[t] = sinf(a); }
    float2 v = src[t];
    float s  = v.x + v.y;
    float s2 = v.x * v.x + v.y * v.y;
    block_reduce2_w16(s, s2, red);
    float mean = s * (1.0f / 2048.0f);
    float var  = s2 * (1.0f / 2048.0f) - mean * mean;
    float sc = rsqrtf(var + 1e-5f);
    v.x = (v.x - mean) * sc;
    v.y = (v.y - mean) * sc;
    ((float2*)(xn + bh * 2048))[t] = v;
    float2 z = {0.f, 0.f};
    ((float2*)(agg + bh * 2048))[t] = z;
    sx[t * 2] = v.x;
    sx[t * 2 + 1] = v.y;
    __syncthreads();
    {
        int oi = t & 511, half = t >> 9;
        int ky = oi >> 5, i = oi & 31;
        float re = 0.f, im = 0.f;
        int w0 = half * 32;
        #pragma unroll 8
        for (int w = w0; w < w0 + 32; ++w) {
            float vv = sx[w * 32 + i];
            int m = (ky * w) & 63;
            re += vv * tc[m];
            im -= vv * ts[m];
        }
        pre_[t] = re;
        pim_[t] = im;
    }
    __syncthreads();
    if (t < 512) {
        Gre[bh * 512 + t] = pre_[t] + pre_[t + 512];
        Gim[bh * 512 + t] = pim_[t] + pim_[t + 512];
    }
}

// ---------------- L2: 0..127 fxy | 128..383 x2 -> osum | 384..2431 ALL GNO chunks ----------------
__global__ __launch_bounds__(256, 4) void k_g1(
        const float* __restrict__ Gre, const float* __restrict__ Gim,
        const float* __restrict__ w1re, const float* __restrict__ w1im,
        const float* __restrict__ w2re, const float* __restrict__ w2im,
        float* __restrict__ Yr, float* __restrict__ Yi,
        const float* __restrict__ ww1, const float* __restrict__ wb1,
        const float* __restrict__ ww2, const float* __restrict__ wb2,
        float* __restrict__ osum,
        const float* __restrict__ ea,
        const float* __restrict__ kw1, const float* __restrict__ kb1,
        const float* __restrict__ kb2,
        const _Float16* __restrict__ whi,
        const float* __restrict__ xn,
        const int* __restrict__ ei,
        float* __restrict__ agg) {
    __shared__ __align__(16) float U[4624];
    __shared__ int ssrc[64], sdst[64];
    int t = threadIdx.x;

    if (blockIdx.x < 128) {
        // ---- fxy ----
        float* tc  = U;
        float* ts  = U + 64;
        float* sXr = U + 128;
        float* sXi = U + 656;
        int bid = blockIdx.x;
        int b = bid >> 5, kxi = bid & 31;
        int kx = kxi + (kxi < 16 ? 0 : 32);
        int x = kxi & 15;
        const float* wre = (kxi < 16) ? w1re : w2re;
        const float* wim = (kxi < 16) ? w1im : w2im;
        if (t < 64) { float a = TWOPI_64 * t; tc[t] = cosf(a); ts[t] = sinf(a); }
        __syncthreads();
        #pragma unroll 1
        for (int rep = 0; rep < 2; ++rep) {
            int oi = rep * 256 + t;
            int ky = oi >> 5, i = oi & 31;
            float re = 0.f, im = 0.f;
            #pragma unroll 8
            for (int h = 0; h < 64; ++h) {
                int gidx = (b * 64 + h) * 512 + ky * 32 + i;
                float gr = Gre[gidx], gi = Gim[gidx];
                int m = (kx * h) & 63;
                float c = tc[m], sv = ts[m];
                re += gr * c + gi * sv;
                im += gi * c - gr * sv;
            }
            sXr[ky * 33 + i] = re;
            sXi[ky * 33 + i] = im;
        }
        __syncthreads();
        #pragma unroll 1
        for (int rep = 0; rep < 2; ++rep) {
            int oi = rep * 256 + t;
            int ky = oi & 15, o = oi >> 4;
            float re = 0.f, im = 0.f;
            #pragma unroll 4
            for (int i = 0; i < 32; ++i) {
                float xr = sXr[ky * 33 + i], xi = sXi[ky * 33 + i];
                int widx = (i * 32 + o) * 256 + x * 16 + ky;
                float wr = wre[widx], wi = wim[widx];
                re += xr * wr - xi * wi;
                im += xr * wi + xi * wr;
            }
            Yr[bid * 512 + ky * 32 + o] = re;
            Yi[bid * 512 + ky * 32 + o] = im;
        }
        return;
    }
    if (blockIdx.x < 384) {
        // ---- x2 = IN(MLP(xn)) -> osum; sHh @ U+2120 ends 4424 <= 4624 ----
        int bh = blockIdx.x - 128;
        float* red = U;
        float* sX = U + 8;                      // 8..2120
        _Float16* sHh = (_Float16*)(U + 2120);  // 2304 floats -> ends 4424
        for (int f = t; f < 2048; f += 256) sX[(f >> 5) * 33 + (f & 31)] = xn[bh * 2048 + f];
        __syncthreads();
        #pragma unroll 1
        for (int rep = 0; rep < 16; ++rep) {
            int idx = rep * 256 + t;
            int w = idx >> 6, k = idx & 63;
            float acc = wb1[k];
            #pragma unroll 4
            for (int c = 0; c < 32; ++c) acc += sX[w * 33 + c] * ww1[c * 64 + k];
            sHh[w * 72 + k] = (_Float16)gelu_f(acc);
        }
        __syncthreads();
        float s = 0.f, s2 = 0.f;
        #pragma unroll 1
        for (int rep = 0; rep < 8; ++rep) {
            int idx = rep * 256 + t;
            int w = idx >> 5, o = idx & 31;
            float acc = wb2[o];
            #pragma unroll 4
            for (int k = 0; k < 64; ++k) acc += (float)sHh[w * 72 + k] * ww2[k * 32 + o];
            sX[w * 33 + o] = acc;
            s += acc; s2 += acc * acc;
        }
        block_reduce2(s, s2, red);
        float mean = s * (1.0f / 2048.0f);
        float sc = rsqrtf(s2 * (1.0f / 2048.0f) - mean * mean + 1e-5f);
        #pragma unroll 1
        for (int rep = 0; rep < 8; ++rep) {
            int idx = rep * 256 + t;
            int w = idx >> 5, o = idx & 31;
            osum[bh * 2048 + idx] = (sX[w * 33 + o] - mean) * sc;
        }
        return;
    }
    gno_body((blockIdx.x - 384) * 64, U, ssrc, sdst,
             ea, kw1, kb1, kb2, whi, xn, ei, agg);
}

// ---------------- L3 (fused, 1024 threads): zx1 + final output, 256 blocks ----------------
// Z phase engages all 1024 threads (2 thread-halves x 16 kxi terms,
// partials in the then-dead sP region).
__global__ __launch_bounds__(1024, 1) void k_g2f(
        const float* __restrict__ Yr, const float* __restrict__ Yi,
        const float* __restrict__ mw1, const float* __restrict__ mb1,
        const float* __restrict__ mw2, const float* __restrict__ mb2,
        const float* __restrict__ osum, const float* __restrict__ agg,
        const float* __restrict__ xn, const float* __restrict__ root,
        const float* __restrict__ gbias, float* __restrict__ out) {
    __shared__ __align__(16) float U[8768];
    int t = threadIdx.x;
    int bh = blockIdx.x;
    int b = bh >> 6, h = bh & 63;
    float* tc  = U;                          // 0..64
    float* ts  = U + 64;                     // 64..128
    float* red = U + 128;                    // 128..160 (32 for 16-wave reduce)
    float* sZr = U + 160;                    // 160..688
    float* sZi = U + 688;                    // 688..1216
    float* sP  = U + 1216;                   // 1216..3328
    float* pZr = U + 1216;                   // Z-phase partials (dead sP region)
    float* pZi = U + 2240;                   // 2240..3264
    _Float16* sHh = (_Float16*)(U + 3328);   // 2304 floats -> 3328..5632
    float* sX  = U + 5632;                   // 5632..7744 (xn, 64x33)
    float* sR  = U + 7744;                   // 7744..8768 (root)

    // early loads for the fused final stage
    for (int f = t; f < 2048; f += 1024) sX[(f >> 5) * 33 + (f & 31)] = xn[bh * 2048 + f];
    sR[t] = root[t];
    float osv[2], agv[2];
    #pragma unroll
    for (int rep = 0; rep < 2; ++rep) {
        int idx = rep * 1024 + t;
        osv[rep] = osum[bh * 2048 + idx];
        agv[rep] = agg[bh * 2048 + idx];
    }
    if (t < 64) { float a = TWOPI_64 * t; tc[t] = cosf(a); ts[t] = sinf(a); }
    __syncthreads();
    {
        int oi = t & 511, half = t >> 9;
        int ky = oi >> 5, o = oi & 31;
        float re = 0.f, im = 0.f;
        int k0 = half * 16;
        #pragma unroll 4
        for (int kxi = k0; kxi < k0 + 16; ++kxi) {
            int kx = kxi + (kxi < 16 ? 0 : 32);
            int m = (kx * h) & 63;
            float c = tc[m], sv = ts[m];
            int yidx = (b * 32 + kxi) * 512 + ky * 32 + o;
            float yr = Yr[yidx], yi = Yi[yidx];
            re += yr * c - yi * sv;
            im += yr * sv + yi * c;
        }
        pZr[t] = re;
        pZi[t] = im;
    }
    __syncthreads();
    if (t < 512) {
        int ky = t >> 5, o = t & 31;
        sZr[ky * 33 + o] = pZr[t] + pZr[t + 512];
        sZi[ky * 33 + o] = pZi[t] + pZi[t + 512];
    }
    __syncthreads();
    float s = 0.f, s2 = 0.f;
    #pragma unroll 1
    for (int rep = 0; rep < 2; ++rep) {
        int idx = rep * 1024 + t;
        int w = idx >> 5, o = idx & 31;
        float acc = sZr[o];  // ky=0: real part only (irfft drops imag of DC bin)
        #pragma unroll
        for (int ky = 1; ky < 16; ++ky) {
            int m = (ky * w) & 63;
            acc += 2.0f * (sZr[ky * 33 + o] * tc[m] - sZi[ky * 33 + o] * ts[m]);
        }
        acc *= (1.0f / 4096.0f);
        sP[w * 33 + o] = acc;
        s += acc; s2 += acc * acc;
    }
    block_reduce2_w16(s, s2, red);
    float mean = s * (1.0f / 2048.0f);
    float sc = rsqrtf(s2 * (1.0f / 2048.0f) - mean * mean + 1e-5f);
    #pragma unroll 1
    for (int rep = 0; rep < 2; ++rep) {
        int idx = rep * 1024 + t;
        int w = idx >> 5, o = idx & 31;
        sP[w * 33 + o] = (sP[w * 33 + o] - mean) * sc;
    }
    __syncthreads();
    #pragma unroll 1
    for (int rep = 0; rep < 4; ++rep) {
        int idx = rep * 1024 + t;
        int w = idx >> 6, k = idx & 63;
        float acc = mb1[k];
        #pragma unroll 4
        for (int c = 0; c < 32; ++c) acc += sP[w * 33 + c] * mw1[c * 64 + k];
        sHh[w * 72 + k] = (_Float16)gelu_f(acc);
    }
    __syncthreads();
    #pragma unroll 1
    for (int rep = 0; rep < 2; ++rep) {
        int idx = rep * 1024 + t;
        int w = idx >> 5, o = idx & 31;
        float x1v = mb2[o];
        #pragma unroll 4
        for (int k = 0; k < 64; ++k) x1v += (float)sHh[w * 72 + k] * mw2[k * 32 + o];
        float val = gbias[o] + osv[rep] + agv[rep] + x1v;
        #pragma unroll 4
        for (int c = 0; c < 32; ++c) val += sX[w * 33 + c] * sR[c * 32 + o];
        out[bh * 2048 + idx] = gelu_f(val);
    }
}

extern "C" void kernel_launch(void* const* d_in, const int* in_sizes, int n_in,
                              void* d_out, int out_size, void* d_ws, size_t ws_size,
                              hipStream_t stream) {
    (void)in_sizes; (void)n_in; (void)out_size; (void)ws_size;
    const float* nodes  = (const float*)d_in[0];
    const int*   eidx   = (const int*)d_in[1];
    const float* eattr  = (const float*)d_in[2];
    const float* w1re   = (const float*)d_in[3];
    const float* w1im   = (const float*)d_in[4];
    const float* w2re   = (const float*)d_in[5];
    const float* w2im   = (const float*)d_in[6];
    const float* mlp_w1 = (const float*)d_in[7];
    const float* mlp_b1 = (const float*)d_in[8];
    const float* mlp_w2 = (const float*)d_in[9];
    const float* mlp_b2 = (const float*)d_in[10];
    const float* wm_w1  = (const float*)d_in[11];
    const float* wm_b1  = (const float*)d_in[12];
    const float* wm_w2  = (const float*)d_in[13];
    const float* wm_b2  = (const float*)d_in[14];
    const float* ker_w1 = (const float*)d_in[15];
    const float* ker_b1 = (const float*)d_in[16];
    const float* ker_w2 = (const float*)d_in[17];
    const float* ker_b2 = (const float*)d_in[18];
    const float* root   = (const float*)d_in[19];
    const float* gbias  = (const float*)d_in[20];
    float* out = (float*)d_out;

    char* ws = (char*)d_ws;
    size_t off = 0;
    auto alloc = [&](size_t bytes) {
        void* p = ws + off;
        off += (bytes + 255) & ~(size_t)255;
        return p;
    };
    float* xn   = (float*)alloc(524288 * 4);
    float* agg  = (float*)alloc(524288 * 4);
    float* osum = (float*)alloc(524288 * 4);
    float* Gre  = (float*)alloc(131072 * 4);
    float* Gim  = (float*)alloc(131072 * 4);
    float* Yr   = (float*)alloc(65536 * 4);
    float* Yi   = (float*)alloc(65536 * 4);
    _Float16* whi = (_Float16*)alloc(65536 * 2);

    k_pre<<<272, 1024, 0, stream>>>(nodes, ker_w2, xn, agg, Gre, Gim, whi);
    k_g1<<<2432, 256, 0, stream>>>(Gre, Gim, w1re, w1im, w2re, w2im, Yr, Yi,
                                   wm_w1, wm_b1, wm_w2, wm_b2, osum,
                                   eattr, ker_w1, ker_b1, ker_b2, whi, xn, eidx, agg);
    k_g2f<<<256, 1024, 0, stream>>>(Yr, Yi, mlp_w1, mlp_b1, mlp_w2, mlp_b2,
                                    osum, agg, xn, root, gbias, out);
}